// Round 3
// baseline (211.327 us; speedup 1.0000x reference)
//
#include <hip/hip_runtime.h>
#include <hip/hip_bf16.h>

typedef unsigned short u16;

#define B_    4
#define T_    4096
#define C_    512
#define H_    8
#define D_    64
#define WIN_  15
#define PAD_  7
#define M_    (B_*T_)      // 16384 rows
#define NQKV  1536
#define KDIM  512

typedef __bf16 bf16x8 __attribute__((ext_vector_type(8)));
typedef float  f32x4  __attribute__((ext_vector_type(4)));

__device__ __forceinline__ u16 f2bf(float f) {
    union { float f; unsigned int i; } c; c.f = f;
    unsigned int lsb = (c.i >> 16) & 1u;
    c.i += 0x7fffu + lsb;                 // round-to-nearest-even
    return (u16)(c.i >> 16);
}
__device__ __forceinline__ float bf2f(u16 u) {
    union { unsigned int i; float f; } c; c.i = ((unsigned int)u) << 16; return c.f;
}

// Swizzled LDS chunk offset, BK=32 (u16 units). Chunk = 16B = 8 bf16.
// slot = sub ^ ((row>>1)&3): fragment reads are conflict-free (2-way = free
// per m136) [R9: SQ_LDS_BANK_CONFLICT 3.1M -> 0]. With global_load_lds the
// swizzle is realized by inverse-permuting the per-lane GLOBAL source
// address (linear LDS dest, both-sides-or-neither).
__device__ __forceinline__ int swz(int row, int sub) {
    return (row * 4 + (sub ^ ((row >> 1) & 3))) * 8;
}

// global->LDS direct DMA, 16B per lane, dest = wave-uniform base + lane*16
__device__ __forceinline__ void gll16(const void* g, void* l) {
    __builtin_amdgcn_global_load_lds(
        (const __attribute__((address_space(1))) void*)g,
        (__attribute__((address_space(3))) void*)l, 16, 0, 0);
}

// ---------------------------------------------------------------------------
// Pack fp32 weights -> bf16 transposed Wt[n][k].
// Wt_qkv rows: [0,512)=Wq cols, [512,1024)=Wkv k-part, [1024,1536)=Wkv v-part.
// ---------------------------------------------------------------------------
__global__ void pack_weights(const float* __restrict__ Wq, const float* __restrict__ Wkv,
                             const float* __restrict__ Wp,
                             u16* __restrict__ Wt_qkv, u16* __restrict__ Wpt)
{
    int idx = blockIdx.x * blockDim.x + threadIdx.x;   // 0 .. 1536*512-1
    int n = idx >> 9;
    int k = idx & 511;
    float w = (n < 512) ? Wq[k * 512 + n] : Wkv[k * 1024 + (n - 512)];
    Wt_qkv[idx] = f2bf(w);
    if (idx < 512 * 512) Wpt[idx] = f2bf(Wp[k * 512 + n]);
}

// ---------------------------------------------------------------------------
// xm = bf16( x_fp32 * mask[row] ) — one-time pass so GEMM1 never re-converts.
// ---------------------------------------------------------------------------
__global__ void apply_mask(const float* __restrict__ x, const float* __restrict__ mask,
                           u16* __restrict__ xm)
{
    int idx = blockIdx.x * blockDim.x + threadIdx.x;   // one per 8 elems
    int e0 = idx * 8;
    float mval = mask[e0 >> 9];
    float4 a = *(const float4*)(x + e0);
    float4 b = *(const float4*)(x + e0 + 4);
    union { uint4 u; u16 s[8]; } o;
    o.s[0] = f2bf(a.x * mval); o.s[1] = f2bf(a.y * mval);
    o.s[2] = f2bf(a.z * mval); o.s[3] = f2bf(a.w * mval);
    o.s[4] = f2bf(b.x * mval); o.s[5] = f2bf(b.y * mval);
    o.s[6] = f2bf(b.z * mval); o.s[7] = f2bf(b.w * mval);
    *(uint4*)(xm + e0) = o.u;
}

// ---------------------------------------------------------------------------
// R14: 256x256 tile, 8 waves (2M x 4N), BK=32, TRIPLE-buffered LDS (96 KB),
// counted-vmcnt pipeline (T3+T4) + setprio around MFMA clusters (T5).
//
// Ledger (proved, no vmcnt(0) in steady state):
//   tile t computes from buf (t%3) and stages tile t+2 into buf ((t+2)%3)
//   (A-half in phase 0, B-half in phase 1; 2 gll each). End-of-tile
//   s_waitcnt vmcnt(4): only tile t+2's 4 loads may remain in flight =>
//   tile t+1's loads (issued one full tile earlier) have landed; the
//   closing s_barrier publishes that across all 8 waves. Buffer being
//   staged was last READ at tile t-1, whose reads completed before its
//   closing barrier => no write-after-read race.
//   Prologue: stage t0+t1 (8 gll), vmcnt(4) (t0 landed), barrier.
//   Tail: t=13 stages t=15 (vmcnt 4); t=14 no stage (vmcnt 0); t=15 none.
// Buffers are STATICALLY NAMED (R12 lesson: runtime index scalarizes reads).
// Swizzle scheme identical to the verified 128-tile kernel (swz + inverse-
// permuted global source). MFMA as mfma(b, a, acc): lane&15 -> C row,
// quad*4+reg -> C col (verified layout, R9).
// K is fixed at 512 (NT=16 K-tiles); both call sites comply.
// ---------------------------------------------------------------------------
template<bool USE_MASK, bool OUT_F32>
__global__ __launch_bounds__(512, 2) void gemm_bt_256(
    const u16* __restrict__ A, int lda,
    const float* __restrict__ amask,  // M fp32
    const u16* __restrict__ Bt,       // N x K row-major bf16 (pre-transposed)
    const float* __restrict__ bias0, const float* __restrict__ bias1,
    void* __restrict__ Cc,            // M x N row-major
    int K, int N)
{
    __shared__ __align__(16) u16 As0[256 * 32];   // 16 KB each, swizzled
    __shared__ __align__(16) u16 As1[256 * 32];
    __shared__ __align__(16) u16 As2[256 * 32];
    __shared__ __align__(16) u16 Bs0[256 * 32];
    __shared__ __align__(16) u16 Bs1[256 * 32];
    __shared__ __align__(16) u16 Bs2[256 * 32];

    const int tid  = threadIdx.x;
    const int wave = tid >> 6;
    const int lane = tid & 63;
    const int row0 = blockIdx.x * 256;
    const int col0 = blockIdx.y * 256;
    const int wm = (wave >> 2) * 128;  // wave's row offset in tile (2 waves)
    const int wn = (wave & 3) * 64;    // wave's col offset in tile (4 waves)

    f32x4 acc[8][4] = {};              // [mi][ni]

    const int quad = lane >> 4;
    const int l16  = lane & 15;

    // Staging: 1024 chunks (16B) per matrix per K-tile; thread covers chunks
    // tid and tid+512. LDS dest chunk c holds source (row=c>>2,
    // sub=(c&3)^((row>>1)&3)) — inverse of the read-side swizzle.
    const int c0 = tid, c1 = tid + 512;
    const int r0l = c0 >> 2, s0 = (c0 & 3) ^ ((r0l >> 1) & 3);
    const int r1l = c1 >> 2, s1 = (c1 & 3) ^ ((r1l >> 1) & 3);
    const u16* Ag0 = A  + (size_t)(row0 + r0l) * lda + s0 * 8;
    const u16* Ag1 = A  + (size_t)(row0 + r1l) * lda + s1 * 8;
    const u16* Bg0 = Bt + (size_t)(col0 + r0l) * K   + s0 * 8;
    const u16* Bg1 = Bt + (size_t)(col0 + r1l) * K   + s1 * 8;
    // wave-uniform LDS bases (u16 units): issue i covers chunks i*512+w*64..
    const int off0 = wave * 512;            // chunk (w*64+lane)  * 8 u16
    const int off1 = 4096 + wave * 512;     // chunk (512+w*64+l) * 8 u16

#define FR(BUF, R) (*(const bf16x8*)&BUF[swz((R) + l16, quad)])

#define TILE(RA, RB, SA, SB, KST, DO, WK)                                    \
    do {                                                                     \
        if (DO) { gll16(Ag0 + (KST), &SA[off0]);                             \
                  gll16(Ag1 + (KST), &SA[off1]); }                           \
        bf16x8 bb[4], aa[4];                                                 \
        _Pragma("unroll")                                                    \
        for (int i = 0; i < 4; i++) bb[i] = FR(RB, wn + i * 16);             \
        _Pragma("unroll")                                                    \
        for (int i = 0; i < 4; i++) aa[i] = FR(RA, wm + i * 16);             \
        __builtin_amdgcn_s_barrier();                                        \
        __builtin_amdgcn_s_setprio(1);                                       \
        _Pragma("unroll")                                                    \
        for (int mi = 0; mi < 4; mi++)                                       \
            _Pragma("unroll")                                                \
            for (int ni = 0; ni < 4; ni++)                                   \
                acc[mi][ni] = __builtin_amdgcn_mfma_f32_16x16x32_bf16(       \
                    bb[ni], aa[mi], acc[mi][ni], 0, 0, 0);                   \
        __builtin_amdgcn_s_setprio(0);                                       \
        __builtin_amdgcn_s_barrier();                                        \
        if (DO) { gll16(Bg0 + (KST), &SB[off0]);                             \
                  gll16(Bg1 + (KST), &SB[off1]); }                           \
        _Pragma("unroll")                                                    \
        for (int i = 0; i < 4; i++) aa[i] = FR(RA, wm + 64 + i * 16);        \
        __builtin_amdgcn_s_barrier();                                        \
        __builtin_amdgcn_s_setprio(1);                                       \
        _Pragma("unroll")                                                    \
        for (int mi = 0; mi < 4; mi++)                                       \
            _Pragma("unroll")                                                \
            for (int ni = 0; ni < 4; ni++)                                   \
                acc[4 + mi][ni] = __builtin_amdgcn_mfma_f32_16x16x32_bf16(   \
                    bb[ni], aa[mi], acc[4 + mi][ni], 0, 0, 0);               \
        __builtin_amdgcn_s_setprio(0);                                       \
        if ((WK) == 4)      asm volatile("s_waitcnt vmcnt(4)" ::: "memory"); \
        else if ((WK) == 0) asm volatile("s_waitcnt vmcnt(0)" ::: "memory"); \
        __builtin_amdgcn_s_barrier();                                        \
    } while (0)

    // prologue: stage tiles 0 and 1; wait tile 0 landed (vmcnt 4 of 8)
    gll16(Ag0,      &As0[off0]); gll16(Ag1,      &As0[off1]);
    gll16(Bg0,      &Bs0[off0]); gll16(Bg1,      &Bs0[off1]);
    gll16(Ag0 + 32, &As1[off0]); gll16(Ag1 + 32, &As1[off1]);
    gll16(Bg0 + 32, &Bs1[off0]); gll16(Bg1 + 32, &Bs1[off1]);
    asm volatile("s_waitcnt vmcnt(4)" ::: "memory");
    __builtin_amdgcn_s_barrier();

    // NT = 16 K-tiles (K = 512). read buf t%3; stage tile t+2 -> buf (t+2)%3
    TILE(As0, Bs0, As2, Bs2,  64, true, 4);   // t=0
    TILE(As1, Bs1, As0, Bs0,  96, true, 4);   // t=1
    TILE(As2, Bs2, As1, Bs1, 128, true, 4);   // t=2
    TILE(As0, Bs0, As2, Bs2, 160, true, 4);   // t=3
    TILE(As1, Bs1, As0, Bs0, 192, true, 4);   // t=4
    TILE(As2, Bs2, As1, Bs1, 224, true, 4);   // t=5
    TILE(As0, Bs0, As2, Bs2, 256, true, 4);   // t=6
    TILE(As1, Bs1, As0, Bs0, 288, true, 4);   // t=7
    TILE(As2, Bs2, As1, Bs1, 320, true, 4);   // t=8
    TILE(As0, Bs0, As2, Bs2, 352, true, 4);   // t=9
    TILE(As1, Bs1, As0, Bs0, 384, true, 4);   // t=10
    TILE(As2, Bs2, As1, Bs1, 416, true, 4);   // t=11
    TILE(As0, Bs0, As2, Bs2, 448, true, 4);   // t=12
    TILE(As1, Bs1, As0, Bs0, 480, true, 4);   // t=13 (stages tile 15)
    TILE(As2, Bs2, As0, Bs0,   0, false, 0);  // t=14 (drain: tile 15 landed)
    TILE(As0, Bs0, As1, Bs1,   0, false, -1); // t=15
#undef TILE
#undef FR

    // ---- epilogue: register-direct vectorized stores (R9, conflicts=0) ----
    #pragma unroll
    for (int mi = 0; mi < 8; mi++) {
        const int row = row0 + wm + mi * 16 + l16;
        float mval = 1.f;
        if (USE_MASK) mval = amask[row];
        #pragma unroll
        for (int ni = 0; ni < 4; ni++) {
            const int colb = col0 + wn + ni * 16 + quad * 4;
            float4 bv = (colb < 512) ? *(const float4*)(bias0 + colb)
                                     : *(const float4*)(bias1 + colb - 512);
            f32x4 v = acc[mi][ni];
            float v0 = v[0] + bv.x, v1 = v[1] + bv.y,
                  v2 = v[2] + bv.z, v3 = v[3] + bv.w;
            if (USE_MASK) { v0 *= mval; v1 *= mval; v2 *= mval; v3 *= mval; }
            if (OUT_F32) {
                float4 o = make_float4(v0, v1, v2, v3);
                *(float4*)((float*)Cc + (size_t)row * N + colb) = o;
            } else {
                union { uint2 u; u16 s[4]; } o;
                o.s[0] = f2bf(v0); o.s[1] = f2bf(v1);
                o.s[2] = f2bf(v2); o.s[3] = f2bf(v3);
                *(uint2*)((u16*)Cc + (size_t)row * N + colb) = o.u;
            }
        }
    }
}

// ---------------------------------------------------------------------------
// Windowed attention: thread-per-(t,h), k/v staged in LDS [jchunk][row].
// Rows outside [0,T) get the bias row. Output in place over the q slot.
// ---------------------------------------------------------------------------
__global__ __launch_bounds__(256) void attn_win2(u16* __restrict__ qkv,
                                                 const float* __restrict__ bkv)
{
    __shared__ uint4 klds[8 * 270];   // [j][row], row = t0-7+row
    __shared__ uint4 vlds[8 * 270];

    const int tid = threadIdx.x;
    const int bid = blockIdx.x;
    const int h  = bid & 7;
    const int b  = (bid >> 3) & 3;
    const int tb = bid >> 5;          // [0,16)
    const int t0 = tb * 256;

    #pragma unroll
    for (int i = 0; i < 9; i++) {
        int idx = i * 256 + tid;
        if (idx < 2160) {
            int row = idx % 270;
            int j   = idx / 270;
            int tt  = t0 - 7 + row;
            uint4 kc, vc;
            if ((unsigned)tt < (unsigned)T_) {
                const u16* g = qkv + ((size_t)b * T_ + tt) * NQKV + 512 + h * 64 + j * 8;
                kc = *(const uint4*)g;
                vc = *(const uint4*)(g + 512);
            } else {
                union { uint4 u; u16 s[8]; } pk, pv;
                #pragma unroll
                for (int e = 0; e < 8; e++) {
                    pk.s[e] = f2bf(bkv[h * 64 + j * 8 + e]);
                    pv.s[e] = f2bf(bkv[512 + h * 64 + j * 8 + e]);
                }
                kc = pk.u; vc = pv.u;
            }
            klds[j * 270 + row] = kc;
            vlds[j * 270 + row] = vc;
        }
    }
    __syncthreads();

    const size_t m = (size_t)b * T_ + t0 + tid;
    u16* qrow = qkv + m * NQKV + h * 64;

    float qf[64];
    #pragma unroll
    for (int j = 0; j < 8; j++) {
        union { uint4 u; u16 s[8]; } t;
        t.u = *(const uint4*)(qrow + j * 8);
        #pragma unroll
        for (int e = 0; e < 8; e++) qf[j * 8 + e] = bf2f(t.s[e]);
    }

    const float scale = 0.042313283f;   // ln(15)/64
    float s[WIN_];
    #pragma unroll
    for (int w = 0; w < WIN_; w++) {
        float acc = 0.f;
        #pragma unroll
        for (int j = 0; j < 8; j++) {
            union { uint4 u; u16 e[8]; } kc;
            kc.u = klds[j * 270 + tid + w];
            #pragma unroll
            for (int e2 = 0; e2 < 8; e2++)
                acc += qf[j * 8 + e2] * bf2f(kc.e[e2]);
        }
        s[w] = acc * scale;
    }

    float mx = s[0];
    #pragma unroll
    for (int w = 1; w < WIN_; w++) mx = fmaxf(mx, s[w]);
    float sum = 0.f;
    #pragma unroll
    for (int w = 0; w < WIN_; w++) { s[w] = __expf(s[w] - mx); sum += s[w]; }
    const float inv = 1.0f / sum;
    #pragma unroll
    for (int w = 0; w < WIN_; w++) s[w] *= inv;

    #pragma unroll
    for (int j = 0; j < 8; j++) {
        float o[8] = {};
        #pragma unroll
        for (int w = 0; w < WIN_; w++) {
            union { uint4 u; u16 e[8]; } vc;
            vc.u = vlds[j * 270 + tid + w];
            #pragma unroll
            for (int e2 = 0; e2 < 8; e2++) o[e2] += s[w] * bf2f(vc.e[e2]);
        }
        union { uint4 u; u16 e[8]; } oc;
        #pragma unroll
        for (int e2 = 0; e2 < 8; e2++) oc.e[e2] = f2bf(o[e2]);
        *(uint4*)(qrow + j * 8) = oc.u;
    }
}

// ---------------------------------------------------------------------------
// Workspace: 66 MiB total.
//   [0, 1.5Mi)    Wt_qkv (1536x512 bf16)
//   [1.5Mi, 2Mi)  Wpt    (512x512 bf16)
//   [2Mi, 18Mi)   xm     (16384x512 bf16)
//   [18Mi, 66Mi)  qkv    (16384x1536 bf16); q section reused for attn output
// ---------------------------------------------------------------------------
extern "C" void kernel_launch(void* const* d_in, const int* in_sizes, int n_in,
                              void* d_out, int out_size, void* d_ws, size_t ws_size,
                              hipStream_t stream)
{
    const float* x    = (const float*)d_in[0];
    const float* mask = (const float*)d_in[1];
    const float* Wq   = (const float*)d_in[2];
    const float* bq   = (const float*)d_in[3];
    const float* Wkv  = (const float*)d_in[4];
    const float* bkv  = (const float*)d_in[5];
    const float* Wp   = (const float*)d_in[6];
    const float* bp   = (const float*)d_in[7];
    float* out = (float*)d_out;

    char* ws = (char*)d_ws;
    u16* Wt_qkv = (u16*)(ws);
    u16* Wpt    = (u16*)(ws + (size_t)(1536 * 1024));
    u16* xm     = (u16*)(ws + (size_t)(2048 * 1024));
    u16* qkv    = (u16*)(ws + (size_t)(18 * 1024 * 1024));

    pack_weights<<<NQKV * KDIM / 256, 256, 0, stream>>>(Wq, Wkv, Wp, Wt_qkv, Wpt);

    apply_mask<<<(M_ * C_) / (8 * 256), 256, 0, stream>>>(x, mask, xm);

    dim3 g1(M_ / 256, NQKV / 256);
    gemm_bt_256<false, false><<<g1, 512, 0, stream>>>(
        xm, KDIM, mask, Wt_qkv, bq, bkv, qkv, KDIM, NQKV);

    attn_win2<<<(T_ / 256) * B_ * H_, 256, 0, stream>>>(qkv, bkv);

    dim3 g2(M_ / 256, C_ / 256);
    gemm_bt_256<true, true><<<g2, 512, 0, stream>>>(
        qkv, NQKV, mask, Wpt, bp, nullptr, out, KDIM, C_);
}

// Round 4
// 198.309 us; speedup vs baseline: 1.0656x; 1.0656x over previous
//
#include <hip/hip_runtime.h>
#include <hip/hip_bf16.h>

typedef unsigned short u16;

#define B_    4
#define T_    4096
#define C_    512
#define H_    8
#define D_    64
#define WIN_  15
#define PAD_  7
#define M_    (B_*T_)      // 16384 rows
#define NQKV  1536
#define KDIM  512

typedef __bf16 bf16x8 __attribute__((ext_vector_type(8)));
typedef float  f32x4  __attribute__((ext_vector_type(4)));

__device__ __forceinline__ u16 f2bf(float f) {
    union { float f; unsigned int i; } c; c.f = f;
    unsigned int lsb = (c.i >> 16) & 1u;
    c.i += 0x7fffu + lsb;                 // round-to-nearest-even
    return (u16)(c.i >> 16);
}
__device__ __forceinline__ float bf2f(u16 u) {
    union { unsigned int i; float f; } c; c.i = ((unsigned int)u) << 16; return c.f;
}

// Swizzled LDS chunk offset, BK=32 (u16 units). Chunk = 16B = 8 bf16.
// slot = sub ^ ((row>>1)&3): fragment reads conflict-free [R9: 3.1M -> 0].
// With global_load_lds staging the swizzle is realized by inverse-permuting
// the per-lane GLOBAL source address (linear LDS dest, both-sides-or-neither).
__device__ __forceinline__ int swz(int row, int sub) {
    return (row * 4 + (sub ^ ((row >> 1) & 3))) * 8;
}

// global->LDS direct DMA, 16B per lane, dest = wave-uniform base + lane*16
__device__ __forceinline__ void gll16(const void* g, void* l) {
    __builtin_amdgcn_global_load_lds(
        (const __attribute__((address_space(1))) void*)g,
        (__attribute__((address_space(3))) void*)l, 16, 0, 0);
}

// ---------------------------------------------------------------------------
// R15: coalesced weight pack via LDS 64x64 tile transpose.
// Old pack read W[k*512+n] with consecutive lanes varying k -> 2KB stride,
// 16x overfetch, latency-bound. Now: coalesced f32 reads (lanes vary n),
// LDS tile[64][65] (padded: read-back banks (tc+nn)%32, 2-way = free),
// coalesced 2B writes over k. 256 tiles: 192 for Wt_qkv, 64 for Wpt.
// ---------------------------------------------------------------------------
__global__ __launch_bounds__(256) void pack_weights_t(
    const float* __restrict__ Wq, const float* __restrict__ Wkv,
    const float* __restrict__ Wp,
    u16* __restrict__ Wt_qkv, u16* __restrict__ Wpt)
{
    __shared__ float tile[64][65];
    const int bid = blockIdx.x;
    const float* src; int srcld; u16* dst; int n0, k0;
    if (bid < 192) {            // Wt_qkv: n0 in [0,1536), k0 in [0,512)
        n0 = (bid % 24) * 64; k0 = (bid / 24) * 64;
        dst = Wt_qkv;
        if (n0 < 512) { src = Wq + n0;          srcld = 512;  }
        else          { src = Wkv + (n0 - 512); srcld = 1024; }
    } else {                    // Wpt
        const int b2 = bid - 192;
        n0 = (b2 % 8) * 64; k0 = (b2 / 8) * 64;
        dst = Wpt; src = Wp + n0; srcld = 512;
    }
    const int tr = threadIdx.x >> 6;   // 0..3
    const int tc = threadIdx.x & 63;
    #pragma unroll
    for (int p = 0; p < 16; p++) {
        const int kk = p * 4 + tr;
        tile[kk][tc] = src[(size_t)(k0 + kk) * srcld + tc];
    }
    __syncthreads();
    #pragma unroll
    for (int p = 0; p < 16; p++) {
        const int nn = p * 4 + tr;
        dst[(size_t)(n0 + nn) * 512 + k0 + tc] = f2bf(tile[tc][nn]);
    }
}

// ---------------------------------------------------------------------------
// xm = bf16( x_fp32 * mask[row] ) — one-time pass so GEMM1 never re-converts.
// ---------------------------------------------------------------------------
__global__ void apply_mask(const float* __restrict__ x, const float* __restrict__ mask,
                           u16* __restrict__ xm)
{
    int idx = blockIdx.x * blockDim.x + threadIdx.x;   // one per 8 elems
    int e0 = idx * 8;
    float mval = mask[e0 >> 9];
    float4 a = *(const float4*)(x + e0);
    float4 b = *(const float4*)(x + e0 + 4);
    union { uint4 u; u16 s[8]; } o;
    o.s[0] = f2bf(a.x * mval); o.s[1] = f2bf(a.y * mval);
    o.s[2] = f2bf(a.z * mval); o.s[3] = f2bf(a.w * mval);
    o.s[4] = f2bf(b.x * mval); o.s[5] = f2bf(b.y * mval);
    o.s[6] = f2bf(b.z * mval); o.s[7] = f2bf(b.w * mval);
    *(uint4*)(xm + e0) = o.u;
}

// ---------------------------------------------------------------------------
// R15 GEMM: proven R2 geometry (128x128 tile, 4 waves, BK=32) + R3's proven
// counted-vmcnt ledger on a TRIPLE buffer (48 KB total -> 3 blocks/CU kept).
// Per K-tile t: stage tile t+2 (4 gll) -> buf (t+2)%3; ds_read buf t%3;
// 16 MFMA; s_waitcnt vmcnt(4) (only t+2's 4 loads may remain => t+1 landed);
// ONE raw s_barrier. No vmcnt(0) in steady state (T4) — removes R2's
// double-__syncthreads full drain (the m97-structure ~20% stall).
// Ledger: prologue stages t0+t1, vmcnt(4) (t0 landed), barrier. Tail: t=13
// stages t15 (vmcnt 4 => t14 landed); t=14 vmcnt(0) (t15 landed); t=15 bare.
// WAR safe: buf staged at tile t was last read at t-1; those ds_reads were
// consumed (lgkmcnt) before t-1's closing barrier.
// Buffers statically named (R12 lesson: runtime index scalarizes reads).
// T1 XCD swizzle: 1D grid, nwg%8==0 at both call sites, bijective chunk map.
// MFMA as mfma(b, a, acc): lane&15 -> C row, quad*4+reg -> C col [R9].
// K fixed at 512 (16 K-tiles); both call sites comply.
// ---------------------------------------------------------------------------
template<bool USE_MASK, bool OUT_F32>
__global__ __launch_bounds__(256) void gemm_bt_128(
    const u16* __restrict__ A, int lda,
    const float* __restrict__ amask,  // M fp32
    const u16* __restrict__ Bt,       // N x K row-major bf16 (pre-transposed)
    const float* __restrict__ bias0, const float* __restrict__ bias1,
    void* __restrict__ Cc,            // M x N row-major
    int K, int N, int gx)             // gx = grid columns (M/128)
{
    __shared__ __align__(16) u16 As0[128 * 32];   // 8 KB each, swizzled
    __shared__ __align__(16) u16 As1[128 * 32];
    __shared__ __align__(16) u16 As2[128 * 32];
    __shared__ __align__(16) u16 Bs0[128 * 32];
    __shared__ __align__(16) u16 Bs1[128 * 32];
    __shared__ __align__(16) u16 Bs2[128 * 32];

    const int tid  = threadIdx.x;
    const int wave = tid >> 6;
    const int lane = tid & 63;

    // T1: bijective XCD swizzle (nwg % 8 == 0 guaranteed by call sites)
    const int nwg = gridDim.x;
    const int cpx = nwg >> 3;
    const int sb  = (blockIdx.x & 7) * cpx + (blockIdx.x >> 3);
    const int row0 = (sb % gx) * 128;
    const int col0 = (sb / gx) * 128;

    const int wm = (wave >> 1) * 64;   // wave's row offset in tile
    const int wn = (wave & 1) * 64;    // wave's col offset in tile

    f32x4 acc[4][4] = {};              // [ci][ri]

    const int quad = lane >> 4;
    const int l16  = lane & 15;

    // Staging: 512 chunks (16B each) per matrix per K-tile; wave w covers
    // chunks [w*128, w*128+128) via two gll issues. LDS dest chunk c holds
    // source (row=c>>2, sub=(c&3)^((row>>1)&3)) — inverse of read swizzle.
    const int cA = wave * 128 + lane;      // issue 0 chunk
    const int cB = cA + 64;                // issue 1 chunk
    const int rA = cA >> 2, sA = (cA & 3) ^ ((rA >> 1) & 3);
    const int rB = cB >> 2, sB = (cB & 3) ^ ((rB >> 1) & 3);
    const u16* Ag0 = A  + (size_t)(row0 + rA) * lda + sA * 8;
    const u16* Ag1 = A  + (size_t)(row0 + rB) * lda + sB * 8;
    const u16* Bg0 = Bt + (size_t)(col0 + rA) * K   + sA * 8;
    const u16* Bg1 = Bt + (size_t)(col0 + rB) * K   + sB * 8;
    const int ldsOff0 = wave * 1024;       // u16 units: chunk w*128
    const int ldsOff1 = wave * 1024 + 512; // chunk w*128 + 64

#define FR(BUF, R) (*(const bf16x8*)&BUF[swz((R) + l16, quad)])

#define STAGE(SA, SB, KST)                         \
    do {                                           \
        gll16(Ag0 + (KST), &SA[ldsOff0]);          \
        gll16(Ag1 + (KST), &SA[ldsOff1]);          \
        gll16(Bg0 + (KST), &SB[ldsOff0]);          \
        gll16(Bg1 + (KST), &SB[ldsOff1]);          \
    } while (0)

// MODE: 1 = staged this tile, wait vmcnt(4); 0 = drain vmcnt(0); -1 = bare
#define TILE(RA, RB, SA, SB, KST, MODE)                                      \
    do {                                                                     \
        if ((MODE) == 1) STAGE(SA, SB, KST);                                 \
        bf16x8 a[4], b[4];                                                   \
        _Pragma("unroll")                                                    \
        for (int i = 0; i < 4; i++) {                                        \
            a[i] = FR(RA, wm + i * 16);                                      \
            b[i] = FR(RB, wn + i * 16);                                      \
        }                                                                    \
        __builtin_amdgcn_s_setprio(1);                                       \
        _Pragma("unroll")                                                    \
        for (int ci = 0; ci < 4; ci++)                                       \
            _Pragma("unroll")                                                \
            for (int ri = 0; ri < 4; ri++)                                   \
                acc[ci][ri] = __builtin_amdgcn_mfma_f32_16x16x32_bf16(       \
                    b[ci], a[ri], acc[ci][ri], 0, 0, 0);                     \
        __builtin_amdgcn_s_setprio(0);                                       \
        if ((MODE) == 1)      asm volatile("s_waitcnt vmcnt(4)" ::: "memory"); \
        else if ((MODE) == 0) asm volatile("s_waitcnt vmcnt(0)" ::: "memory"); \
        if ((MODE) >= 0) __builtin_amdgcn_s_barrier();                       \
    } while (0)

    // prologue: stage tiles 0 and 1; wait tile 0 landed (vmcnt 4 of 8)
    STAGE(As0, Bs0, 0);
    STAGE(As1, Bs1, 32);
    asm volatile("s_waitcnt vmcnt(4)" ::: "memory");
    __builtin_amdgcn_s_barrier();

    // 16 K-tiles (K = 512): read buf t%3, stage tile t+2 -> buf (t+2)%3
    TILE(As0, Bs0, As2, Bs2,  64, 1);   // t=0
    TILE(As1, Bs1, As0, Bs0,  96, 1);   // t=1
    TILE(As2, Bs2, As1, Bs1, 128, 1);   // t=2
    TILE(As0, Bs0, As2, Bs2, 160, 1);   // t=3
    TILE(As1, Bs1, As0, Bs0, 192, 1);   // t=4
    TILE(As2, Bs2, As1, Bs1, 224, 1);   // t=5
    TILE(As0, Bs0, As2, Bs2, 256, 1);   // t=6
    TILE(As1, Bs1, As0, Bs0, 288, 1);   // t=7
    TILE(As2, Bs2, As1, Bs1, 320, 1);   // t=8
    TILE(As0, Bs0, As2, Bs2, 352, 1);   // t=9
    TILE(As1, Bs1, As0, Bs0, 384, 1);   // t=10
    TILE(As2, Bs2, As1, Bs1, 416, 1);   // t=11
    TILE(As0, Bs0, As2, Bs2, 448, 1);   // t=12
    TILE(As1, Bs1, As0, Bs0, 480, 1);   // t=13 (stages tile 15 -> buf0)
    TILE(As2, Bs2, As0, Bs0,   0, 0);   // t=14 (drain: tile 15 landed)
    TILE(As0, Bs0, As1, Bs1,   0, -1);  // t=15
#undef TILE
#undef STAGE
#undef FR

    // ---- epilogue: register-direct vectorized stores (R9, conflicts=0) ----
    #pragma unroll
    for (int ri = 0; ri < 4; ri++) {
        const int row = row0 + wm + ri * 16 + l16;
        float mval = 1.f;
        if (USE_MASK) mval = amask[row];
        #pragma unroll
        for (int ci = 0; ci < 4; ci++) {
            const int colb = col0 + wn + ci * 16 + quad * 4;
            float4 bv = (colb < 512) ? *(const float4*)(bias0 + colb)
                                     : *(const float4*)(bias1 + colb - 512);
            f32x4 v = acc[ci][ri];
            float v0 = v[0] + bv.x, v1 = v[1] + bv.y,
                  v2 = v[2] + bv.z, v3 = v[3] + bv.w;
            if (USE_MASK) { v0 *= mval; v1 *= mval; v2 *= mval; v3 *= mval; }
            if (OUT_F32) {
                float4 o = make_float4(v0, v1, v2, v3);
                *(float4*)((float*)Cc + (size_t)row * N + colb) = o;
            } else {
                union { uint2 u; u16 s[4]; } o;
                o.s[0] = f2bf(v0); o.s[1] = f2bf(v1);
                o.s[2] = f2bf(v2); o.s[3] = f2bf(v3);
                *(uint2*)((u16*)Cc + (size_t)row * N + colb) = o.u;
            }
        }
    }
}

// ---------------------------------------------------------------------------
// Windowed attention: thread-per-(t,h), k/v staged in LDS [jchunk][row].
// Rows outside [0,T) get the bias row. Output in place over the q slot.
// ---------------------------------------------------------------------------
__global__ __launch_bounds__(256) void attn_win2(u16* __restrict__ qkv,
                                                 const float* __restrict__ bkv)
{
    __shared__ uint4 klds[8 * 270];   // [j][row], row = t0-7+row
    __shared__ uint4 vlds[8 * 270];

    const int tid = threadIdx.x;
    const int bid = blockIdx.x;
    const int h  = bid & 7;
    const int b  = (bid >> 3) & 3;
    const int tb = bid >> 5;          // [0,16)
    const int t0 = tb * 256;

    #pragma unroll
    for (int i = 0; i < 9; i++) {
        int idx = i * 256 + tid;
        if (idx < 2160) {
            int row = idx % 270;
            int j   = idx / 270;
            int tt  = t0 - 7 + row;
            uint4 kc, vc;
            if ((unsigned)tt < (unsigned)T_) {
                const u16* g = qkv + ((size_t)b * T_ + tt) * NQKV + 512 + h * 64 + j * 8;
                kc = *(const uint4*)g;
                vc = *(const uint4*)(g + 512);
            } else {
                union { uint4 u; u16 s[8]; } pk, pv;
                #pragma unroll
                for (int e = 0; e < 8; e++) {
                    pk.s[e] = f2bf(bkv[h * 64 + j * 8 + e]);
                    pv.s[e] = f2bf(bkv[512 + h * 64 + j * 8 + e]);
                }
                kc = pk.u; vc = pv.u;
            }
            klds[j * 270 + row] = kc;
            vlds[j * 270 + row] = vc;
        }
    }
    __syncthreads();

    const size_t m = (size_t)b * T_ + t0 + tid;
    u16* qrow = qkv + m * NQKV + h * 64;

    float qf[64];
    #pragma unroll
    for (int j = 0; j < 8; j++) {
        union { uint4 u; u16 s[8]; } t;
        t.u = *(const uint4*)(qrow + j * 8);
        #pragma unroll
        for (int e = 0; e < 8; e++) qf[j * 8 + e] = bf2f(t.s[e]);
    }

    const float scale = 0.042313283f;   // ln(15)/64
    float s[WIN_];
    #pragma unroll
    for (int w = 0; w < WIN_; w++) {
        float acc = 0.f;
        #pragma unroll
        for (int j = 0; j < 8; j++) {
            union { uint4 u; u16 e[8]; } kc;
            kc.u = klds[j * 270 + tid + w];
            #pragma unroll
            for (int e2 = 0; e2 < 8; e2++)
                acc += qf[j * 8 + e2] * bf2f(kc.e[e2]);
        }
        s[w] = acc * scale;
    }

    float mx = s[0];
    #pragma unroll
    for (int w = 1; w < WIN_; w++) mx = fmaxf(mx, s[w]);
    float sum = 0.f;
    #pragma unroll
    for (int w = 0; w < WIN_; w++) { s[w] = __expf(s[w] - mx); sum += s[w]; }
    const float inv = 1.0f / sum;
    #pragma unroll
    for (int w = 0; w < WIN_; w++) s[w] *= inv;

    #pragma unroll
    for (int j = 0; j < 8; j++) {
        float o[8] = {};
        #pragma unroll
        for (int w = 0; w < WIN_; w++) {
            union { uint4 u; u16 e[8]; } vc;
            vc.u = vlds[j * 270 + tid + w];
            #pragma unroll
            for (int e2 = 0; e2 < 8; e2++) o[e2] += s[w] * bf2f(vc.e[e2]);
        }
        union { uint4 u; u16 e[8]; } oc;
        #pragma unroll
        for (int e2 = 0; e2 < 8; e2++) oc.e[e2] = f2bf(o[e2]);
        *(uint4*)(qrow + j * 8) = oc.u;
    }
}

// ---------------------------------------------------------------------------
// Workspace: 66 MiB total.
//   [0, 1.5Mi)    Wt_qkv (1536x512 bf16)
//   [1.5Mi, 2Mi)  Wpt    (512x512 bf16)
//   [2Mi, 18Mi)   xm     (16384x512 bf16)
//   [18Mi, 66Mi)  qkv    (16384x1536 bf16); q section reused for attn output
// ---------------------------------------------------------------------------
extern "C" void kernel_launch(void* const* d_in, const int* in_sizes, int n_in,
                              void* d_out, int out_size, void* d_ws, size_t ws_size,
                              hipStream_t stream)
{
    const float* x    = (const float*)d_in[0];
    const float* mask = (const float*)d_in[1];
    const float* Wq   = (const float*)d_in[2];
    const float* bq   = (const float*)d_in[3];
    const float* Wkv  = (const float*)d_in[4];
    const float* bkv  = (const float*)d_in[5];
    const float* Wp   = (const float*)d_in[6];
    const float* bp   = (const float*)d_in[7];
    float* out = (float*)d_out;

    char* ws = (char*)d_ws;
    u16* Wt_qkv = (u16*)(ws);
    u16* Wpt    = (u16*)(ws + (size_t)(1536 * 1024));
    u16* xm     = (u16*)(ws + (size_t)(2048 * 1024));
    u16* qkv    = (u16*)(ws + (size_t)(18 * 1024 * 1024));

    pack_weights_t<<<256, 256, 0, stream>>>(Wq, Wkv, Wp, Wt_qkv, Wpt);

    apply_mask<<<(M_ * C_) / (8 * 256), 256, 0, stream>>>(x, mask, xm);

    // 1D grids (nwg % 8 == 0 for the XCD swizzle): 1536 and 512 blocks
    gemm_bt_128<false, false><<<(M_ / 128) * (NQKV / 128), 256, 0, stream>>>(
        xm, KDIM, mask, Wt_qkv, bq, bkv, qkv, KDIM, NQKV, M_ / 128);

    attn_win2<<<(T_ / 256) * B_ * H_, 256, 0, stream>>>(qkv, bkv);

    gemm_bt_128<true, true><<<(M_ / 128) * (C_ / 128), 256, 0, stream>>>(
        qkv, NQKV, mask, Wpt, bp, nullptr, out, KDIM, C_, M_ / 128);
}

// Round 5
// 192.548 us; speedup vs baseline: 1.0975x; 1.0299x over previous
//
#include <hip/hip_runtime.h>
#include <hip/hip_bf16.h>

typedef unsigned short u16;

#define B_    4
#define T_    4096
#define C_    512
#define H_    8
#define D_    64
#define WIN_  15
#define PAD_  7
#define M_    (B_*T_)      // 16384 rows
#define NQKV  1536
#define KDIM  512

typedef __bf16 bf16x8 __attribute__((ext_vector_type(8)));
typedef float  f32x4  __attribute__((ext_vector_type(4)));

__device__ __forceinline__ u16 f2bf(float f) {
    union { float f; unsigned int i; } c; c.f = f;
    unsigned int lsb = (c.i >> 16) & 1u;
    c.i += 0x7fffu + lsb;                 // round-to-nearest-even
    return (u16)(c.i >> 16);
}
__device__ __forceinline__ float bf2f(u16 u) {
    union { unsigned int i; float f; } c; c.i = ((unsigned int)u) << 16; return c.f;
}

// Swizzled LDS chunk offset, BK=32 (u16 units). Chunk = 16B = 8 bf16.
// slot = sub ^ ((row>>1)&3): fragment reads conflict-free [R9: 3.1M -> 0].
// With global_load_lds staging the swizzle is realized by inverse-permuting
// the per-lane GLOBAL source address (linear LDS dest, both-sides-or-neither).
__device__ __forceinline__ int swz(int row, int sub) {
    return (row * 4 + (sub ^ ((row >> 1) & 3))) * 8;
}

// global->LDS direct DMA, 16B per lane, dest = wave-uniform base + lane*16
__device__ __forceinline__ void gll16(const void* g, void* l) {
    __builtin_amdgcn_global_load_lds(
        (const __attribute__((address_space(1))) void*)g,
        (__attribute__((address_space(3))) void*)l, 16, 0, 0);
}

// ---------------------------------------------------------------------------
// R15: coalesced weight pack via LDS 64x64 tile transpose. (kept from R4)
// ---------------------------------------------------------------------------
__global__ __launch_bounds__(256) void pack_weights_t(
    const float* __restrict__ Wq, const float* __restrict__ Wkv,
    const float* __restrict__ Wp,
    u16* __restrict__ Wt_qkv, u16* __restrict__ Wpt)
{
    __shared__ float tile[64][65];
    const int bid = blockIdx.x;
    const float* src; int srcld; u16* dst; int n0, k0;
    if (bid < 192) {            // Wt_qkv: n0 in [0,1536), k0 in [0,512)
        n0 = (bid % 24) * 64; k0 = (bid / 24) * 64;
        dst = Wt_qkv;
        if (n0 < 512) { src = Wq + n0;          srcld = 512;  }
        else          { src = Wkv + (n0 - 512); srcld = 1024; }
    } else {                    // Wpt
        const int b2 = bid - 192;
        n0 = (b2 % 8) * 64; k0 = (b2 / 8) * 64;
        dst = Wpt; src = Wp + n0; srcld = 512;
    }
    const int tr = threadIdx.x >> 6;   // 0..3
    const int tc = threadIdx.x & 63;
    #pragma unroll
    for (int p = 0; p < 16; p++) {
        const int kk = p * 4 + tr;
        tile[kk][tc] = src[(size_t)(k0 + kk) * srcld + tc];
    }
    __syncthreads();
    #pragma unroll
    for (int p = 0; p < 16; p++) {
        const int nn = p * 4 + tr;
        dst[(size_t)(n0 + nn) * 512 + k0 + tc] = f2bf(tile[tc][nn]);
    }
}

// ---------------------------------------------------------------------------
// xm = bf16( x_fp32 * mask[row] ) — one-time pass so GEMM1 never re-converts.
// ---------------------------------------------------------------------------
__global__ void apply_mask(const float* __restrict__ x, const float* __restrict__ mask,
                           u16* __restrict__ xm)
{
    int idx = blockIdx.x * blockDim.x + threadIdx.x;   // one per 8 elems
    int e0 = idx * 8;
    float mval = mask[e0 >> 9];
    float4 a = *(const float4*)(x + e0);
    float4 b = *(const float4*)(x + e0 + 4);
    union { uint4 u; u16 s[8]; } o;
    o.s[0] = f2bf(a.x * mval); o.s[1] = f2bf(a.y * mval);
    o.s[2] = f2bf(a.z * mval); o.s[3] = f2bf(a.w * mval);
    o.s[4] = f2bf(b.x * mval); o.s[5] = f2bf(b.y * mval);
    o.s[6] = f2bf(b.z * mval); o.s[7] = f2bf(b.w * mval);
    *(uint4*)(xm + e0) = o.u;
}

// ---------------------------------------------------------------------------
// R16 GEMM: R2 geometry + 2D grid (NO XCD swizzle — R4 post-mortem: natural
// round-robin dispatch with gridDim.x=128 (%8==0) already pins row-block r
// to XCD r%8 every column sweep, so each XCD re-reads only its 2MB of A
// panels from its own L2. The R4 swizzle broke this: FETCH 21.9->99.9 MB.)
// Kept from R4: triple-buffer counted-vmcnt ledger, one s_barrier per K-step.
//   tile t: stage t+2 -> buf (t+2)%3 (4 gll), ds_read buf t%3, 16 MFMA,
//   s_waitcnt vmcnt(4) (=> tile t+1 landed; never 0 in steady state), barrier.
//   Prologue stages t0+t1, vmcnt(4), barrier. Tail t=14 drains vmcnt(0).
//   WAR safe: buf staged at t was last read at t-1, before t-1's barrier.
// Buffers statically named (R12 lesson: runtime index scalarizes ds_reads).
// MFMA as mfma(b, a, acc): lane&15 -> C row, quad*4+reg -> C col [R9].
// K fixed at 512 (16 K-tiles); both call sites comply.
// ---------------------------------------------------------------------------
template<bool USE_MASK, bool OUT_F32>
__global__ __launch_bounds__(256) void gemm_bt_128(
    const u16* __restrict__ A, int lda,
    const float* __restrict__ amask,  // M fp32
    const u16* __restrict__ Bt,       // N x K row-major bf16 (pre-transposed)
    const float* __restrict__ bias0, const float* __restrict__ bias1,
    void* __restrict__ Cc,            // M x N row-major
    int K, int N)
{
    __shared__ __align__(16) u16 As0[128 * 32];   // 8 KB each, swizzled
    __shared__ __align__(16) u16 As1[128 * 32];
    __shared__ __align__(16) u16 As2[128 * 32];
    __shared__ __align__(16) u16 Bs0[128 * 32];
    __shared__ __align__(16) u16 Bs1[128 * 32];
    __shared__ __align__(16) u16 Bs2[128 * 32];

    const int tid  = threadIdx.x;
    const int wave = tid >> 6;
    const int lane = tid & 63;
    const int row0 = blockIdx.x * 128;
    const int col0 = blockIdx.y * 128;

    const int wm = (wave >> 1) * 64;   // wave's row offset in tile
    const int wn = (wave & 1) * 64;    // wave's col offset in tile

    f32x4 acc[4][4] = {};              // [ci][ri]

    const int quad = lane >> 4;
    const int l16  = lane & 15;

    // Staging: 512 chunks (16B each) per matrix per K-tile; wave w covers
    // chunks [w*128, w*128+128) via two gll issues. LDS dest chunk c holds
    // source (row=c>>2, sub=(c&3)^((row>>1)&3)) — inverse of read swizzle.
    const int cA = wave * 128 + lane;      // issue 0 chunk
    const int cB = cA + 64;                // issue 1 chunk
    const int rA = cA >> 2, sA = (cA & 3) ^ ((rA >> 1) & 3);
    const int rB = cB >> 2, sB = (cB & 3) ^ ((rB >> 1) & 3);
    const u16* Ag0 = A  + (size_t)(row0 + rA) * lda + sA * 8;
    const u16* Ag1 = A  + (size_t)(row0 + rB) * lda + sB * 8;
    const u16* Bg0 = Bt + (size_t)(col0 + rA) * K   + sA * 8;
    const u16* Bg1 = Bt + (size_t)(col0 + rB) * K   + sB * 8;
    const int ldsOff0 = wave * 1024;       // u16 units: chunk w*128
    const int ldsOff1 = wave * 1024 + 512; // chunk w*128 + 64

#define FR(BUF, R) (*(const bf16x8*)&BUF[swz((R) + l16, quad)])

#define STAGE(SA, SB, KST)                         \
    do {                                           \
        gll16(Ag0 + (KST), &SA[ldsOff0]);          \
        gll16(Ag1 + (KST), &SA[ldsOff1]);          \
        gll16(Bg0 + (KST), &SB[ldsOff0]);          \
        gll16(Bg1 + (KST), &SB[ldsOff1]);          \
    } while (0)

// MODE: 1 = staged this tile, wait vmcnt(4); 0 = drain vmcnt(0); -1 = bare
#define TILE(RA, RB, SA, SB, KST, MODE)                                      \
    do {                                                                     \
        if ((MODE) == 1) STAGE(SA, SB, KST);                                 \
        bf16x8 a[4], b[4];                                                   \
        _Pragma("unroll")                                                    \
        for (int i = 0; i < 4; i++) {                                        \
            a[i] = FR(RA, wm + i * 16);                                      \
            b[i] = FR(RB, wn + i * 16);                                      \
        }                                                                    \
        __builtin_amdgcn_s_setprio(1);                                       \
        _Pragma("unroll")                                                    \
        for (int ci = 0; ci < 4; ci++)                                       \
            _Pragma("unroll")                                                \
            for (int ri = 0; ri < 4; ri++)                                   \
                acc[ci][ri] = __builtin_amdgcn_mfma_f32_16x16x32_bf16(       \
                    b[ci], a[ri], acc[ci][ri], 0, 0, 0);                     \
        __builtin_amdgcn_s_setprio(0);                                       \
        if ((MODE) == 1)      asm volatile("s_waitcnt vmcnt(4)" ::: "memory"); \
        else if ((MODE) == 0) asm volatile("s_waitcnt vmcnt(0)" ::: "memory"); \
        if ((MODE) >= 0) __builtin_amdgcn_s_barrier();                       \
    } while (0)

    // prologue: stage tiles 0 and 1; wait tile 0 landed (vmcnt 4 of 8)
    STAGE(As0, Bs0, 0);
    STAGE(As1, Bs1, 32);
    asm volatile("s_waitcnt vmcnt(4)" ::: "memory");
    __builtin_amdgcn_s_barrier();

    // 16 K-tiles (K = 512): read buf t%3, stage tile t+2 -> buf (t+2)%3
    TILE(As0, Bs0, As2, Bs2,  64, 1);   // t=0
    TILE(As1, Bs1, As0, Bs0,  96, 1);   // t=1
    TILE(As2, Bs2, As1, Bs1, 128, 1);   // t=2
    TILE(As0, Bs0, As2, Bs2, 160, 1);   // t=3
    TILE(As1, Bs1, As0, Bs0, 192, 1);   // t=4
    TILE(As2, Bs2, As1, Bs1, 224, 1);   // t=5
    TILE(As0, Bs0, As2, Bs2, 256, 1);   // t=6
    TILE(As1, Bs1, As0, Bs0, 288, 1);   // t=7
    TILE(As2, Bs2, As1, Bs1, 320, 1);   // t=8
    TILE(As0, Bs0, As2, Bs2, 352, 1);   // t=9
    TILE(As1, Bs1, As0, Bs0, 384, 1);   // t=10
    TILE(As2, Bs2, As1, Bs1, 416, 1);   // t=11
    TILE(As0, Bs0, As2, Bs2, 448, 1);   // t=12
    TILE(As1, Bs1, As0, Bs0, 480, 1);   // t=13 (stages tile 15 -> buf0)
    TILE(As2, Bs2, As0, Bs0,   0, 0);   // t=14 (drain: tile 15 landed)
    TILE(As0, Bs0, As1, Bs1,   0, -1);  // t=15
#undef TILE
#undef STAGE
#undef FR

    // ---- epilogue: register-direct vectorized stores (R9, conflicts=0) ----
    #pragma unroll
    for (int ri = 0; ri < 4; ri++) {
        const int row = row0 + wm + ri * 16 + l16;
        float mval = 1.f;
        if (USE_MASK) mval = amask[row];
        #pragma unroll
        for (int ci = 0; ci < 4; ci++) {
            const int colb = col0 + wn + ci * 16 + quad * 4;
            float4 bv = (colb < 512) ? *(const float4*)(bias0 + colb)
                                     : *(const float4*)(bias1 + colb - 512);
            f32x4 v = acc[ci][ri];
            float v0 = v[0] + bv.x, v1 = v[1] + bv.y,
                  v2 = v[2] + bv.z, v3 = v[3] + bv.w;
            if (USE_MASK) { v0 *= mval; v1 *= mval; v2 *= mval; v3 *= mval; }
            if (OUT_F32) {
                float4 o = make_float4(v0, v1, v2, v3);
                *(float4*)((float*)Cc + (size_t)row * N + colb) = o;
            } else {
                union { uint2 u; u16 s[4]; } o;
                o.s[0] = f2bf(v0); o.s[1] = f2bf(v1);
                o.s[2] = f2bf(v2); o.s[3] = f2bf(v3);
                *(uint2*)((u16*)Cc + (size_t)row * N + colb) = o.u;
            }
        }
    }
}

// ---------------------------------------------------------------------------
// Windowed attention: thread-per-(t,h), k/v staged in LDS [jchunk][row].
// Rows outside [0,T) get the bias row. Output in place over the q slot.
// ---------------------------------------------------------------------------
__global__ __launch_bounds__(256) void attn_win2(u16* __restrict__ qkv,
                                                 const float* __restrict__ bkv)
{
    __shared__ uint4 klds[8 * 270];   // [j][row], row = t0-7+row
    __shared__ uint4 vlds[8 * 270];

    const int tid = threadIdx.x;
    const int bid = blockIdx.x;
    const int h  = bid & 7;
    const int b  = (bid >> 3) & 3;
    const int tb = bid >> 5;          // [0,16)
    const int t0 = tb * 256;

    #pragma unroll
    for (int i = 0; i < 9; i++) {
        int idx = i * 256 + tid;
        if (idx < 2160) {
            int row = idx % 270;
            int j   = idx / 270;
            int tt  = t0 - 7 + row;
            uint4 kc, vc;
            if ((unsigned)tt < (unsigned)T_) {
                const u16* g = qkv + ((size_t)b * T_ + tt) * NQKV + 512 + h * 64 + j * 8;
                kc = *(const uint4*)g;
                vc = *(const uint4*)(g + 512);
            } else {
                union { uint4 u; u16 s[8]; } pk, pv;
                #pragma unroll
                for (int e = 0; e < 8; e++) {
                    pk.s[e] = f2bf(bkv[h * 64 + j * 8 + e]);
                    pv.s[e] = f2bf(bkv[512 + h * 64 + j * 8 + e]);
                }
                kc = pk.u; vc = pv.u;
            }
            klds[j * 270 + row] = kc;
            vlds[j * 270 + row] = vc;
        }
    }
    __syncthreads();

    const size_t m = (size_t)b * T_ + t0 + tid;
    u16* qrow = qkv + m * NQKV + h * 64;

    float qf[64];
    #pragma unroll
    for (int j = 0; j < 8; j++) {
        union { uint4 u; u16 s[8]; } t;
        t.u = *(const uint4*)(qrow + j * 8);
        #pragma unroll
        for (int e = 0; e < 8; e++) qf[j * 8 + e] = bf2f(t.s[e]);
    }

    const float scale = 0.042313283f;   // ln(15)/64
    float s[WIN_];
    #pragma unroll
    for (int w = 0; w < WIN_; w++) {
        float acc = 0.f;
        #pragma unroll
        for (int j = 0; j < 8; j++) {
            union { uint4 u; u16 e[8]; } kc;
            kc.u = klds[j * 270 + tid + w];
            #pragma unroll
            for (int e2 = 0; e2 < 8; e2++)
                acc += qf[j * 8 + e2] * bf2f(kc.e[e2]);
        }
        s[w] = acc * scale;
    }

    float mx = s[0];
    #pragma unroll
    for (int w = 1; w < WIN_; w++) mx = fmaxf(mx, s[w]);
    float sum = 0.f;
    #pragma unroll
    for (int w = 0; w < WIN_; w++) { s[w] = __expf(s[w] - mx); sum += s[w]; }
    const float inv = 1.0f / sum;
    #pragma unroll
    for (int w = 0; w < WIN_; w++) s[w] *= inv;

    #pragma unroll
    for (int j = 0; j < 8; j++) {
        float o[8] = {};
        #pragma unroll
        for (int w = 0; w < WIN_; w++) {
            union { uint4 u; u16 e[8]; } vc;
            vc.u = vlds[j * 270 + tid + w];
            #pragma unroll
            for (int e2 = 0; e2 < 8; e2++) o[e2] += s[w] * bf2f(vc.e[e2]);
        }
        union { uint4 u; u16 e[8]; } oc;
        #pragma unroll
        for (int e2 = 0; e2 < 8; e2++) oc.e[e2] = f2bf(o[e2]);
        *(uint4*)(qrow + j * 8) = oc.u;
    }
}

// ---------------------------------------------------------------------------
// Workspace: 66 MiB total.
//   [0, 1.5Mi)    Wt_qkv (1536x512 bf16)
//   [1.5Mi, 2Mi)  Wpt    (512x512 bf16)
//   [2Mi, 18Mi)   xm     (16384x512 bf16)
//   [18Mi, 66Mi)  qkv    (16384x1536 bf16); q section reused for attn output
// ---------------------------------------------------------------------------
extern "C" void kernel_launch(void* const* d_in, const int* in_sizes, int n_in,
                              void* d_out, int out_size, void* d_ws, size_t ws_size,
                              hipStream_t stream)
{
    const float* x    = (const float*)d_in[0];
    const float* mask = (const float*)d_in[1];
    const float* Wq   = (const float*)d_in[2];
    const float* bq   = (const float*)d_in[3];
    const float* Wkv  = (const float*)d_in[4];
    const float* bkv  = (const float*)d_in[5];
    const float* Wp   = (const float*)d_in[6];
    const float* bp   = (const float*)d_in[7];
    float* out = (float*)d_out;

    char* ws = (char*)d_ws;
    u16* Wt_qkv = (u16*)(ws);
    u16* Wpt    = (u16*)(ws + (size_t)(1536 * 1024));
    u16* xm     = (u16*)(ws + (size_t)(2048 * 1024));
    u16* qkv    = (u16*)(ws + (size_t)(18 * 1024 * 1024));

    pack_weights_t<<<256, 256, 0, stream>>>(Wq, Wkv, Wp, Wt_qkv, Wpt);

    apply_mask<<<(M_ * C_) / (8 * 256), 256, 0, stream>>>(x, mask, xm);

    // 2D grids: gridDim.x = 128 row-blocks (%8==0) -> row-block r lands on
    // XCD r%8 every column sweep; per-XCD A working set 2MB fits L2. [R16]
    dim3 g1(M_ / 128, NQKV / 128);
    gemm_bt_128<false, false><<<g1, 256, 0, stream>>>(
        xm, KDIM, mask, Wt_qkv, bq, bkv, qkv, KDIM, NQKV);

    attn_win2<<<(T_ / 256) * B_ * H_, 256, 0, stream>>>(qkv, bkv);

    dim3 g2(M_ / 128, C_ / 128);
    gemm_bt_128<true, true><<<g2, 256, 0, stream>>>(
        qkv, NQKV, mask, Wpt, bp, nullptr, out, KDIM, C_);
}